// Round 15
// baseline (1091.071 us; speedup 1.0000x reference)
//
#include <hip/hip_runtime.h>
#include <hip/hip_fp16.h>
#include <math.h>

#define DCONV 16
#define BSH 8            // nodes per bucket = 256
#define GPART 512        // partition blocks (parallelism for hist/scatter)
#define GSH 9            // log2(GPART)
#define MAXNB 512
#define SCAP 6912        // >= chunk (6250) : per-block LDS sort capacity

// ---------------- bucketed edge-partition build ----------------

__global__ void __launch_bounds__(512) k_hist(const int* __restrict__ ei, int E,
                                              int nb_buckets, int chunk,
                                              int* __restrict__ cnt) {
  __shared__ int hist[MAXNB];
  int g = blockIdx.x;
  for (int i = threadIdx.x; i < nb_buckets; i += 512) hist[i] = 0;
  __syncthreads();
  int e0 = g * chunk, e1 = min(e0 + chunk, E);
  for (int e = e0 + threadIdx.x; e < e1; e += 512)
    atomicAdd(&hist[ei[E + e] >> BSH], 1);
  __syncthreads();
  for (int i = threadIdx.x; i < nb_buckets; i += 512)
    cnt[i * GPART + g] = hist[i];
}

__global__ void k_block_sums(const int* __restrict__ in, int n, int* __restrict__ part) {
  int i = blockIdx.x * 256 + threadIdx.x;
  int v = (i < n) ? in[i] : 0;
  #pragma unroll
  for (int off = 32; off > 0; off >>= 1) v += __shfl_down(v, off, 64);
  __shared__ int ws[4];
  if ((threadIdx.x & 63) == 0) ws[threadIdx.x >> 6] = v;
  __syncthreads();
  if (threadIdx.x == 0) part[blockIdx.x] = ws[0] + ws[1] + ws[2] + ws[3];
}

// single block, 1024 threads; nb <= 1024
__global__ void k_scan_part(int* __restrict__ part, int nb) {
  __shared__ int s[1024];
  int t = threadIdx.x;
  int v = (t < nb) ? part[t] : 0;
  s[t] = v;
  __syncthreads();
  for (int off = 1; off < 1024; off <<= 1) {
    int u = (t >= off) ? s[t - off] : 0;
    __syncthreads();
    s[t] += u;
    __syncthreads();
  }
  if (t < nb) part[t] = s[t] - v;  // exclusive prefix
}

// writes TRANSPOSED offsets: offT[g * nb_buckets + b]
__global__ void k_excl_apply(const int* __restrict__ in, int n, const int* __restrict__ part,
                             int* __restrict__ outT, int nb_buckets) {
  __shared__ int s[256];
  int t = threadIdx.x;
  int i = blockIdx.x * 256 + t;
  int v = (i < n) ? in[i] : 0;
  s[t] = v;
  __syncthreads();
  for (int off = 1; off < 256; off <<= 1) {
    int u = (t >= off) ? s[t - off] : 0;
    __syncthreads();
    s[t] += u;
    __syncthreads();
  }
  if (i < n) {
    int excl = s[t] - v + part[blockIdx.x];
    int b = i >> GSH;
    int g = i & (GPART - 1);
    outT[g * nb_buckets + b] = excl;
  }
}

// LDS batch-sort scatter: bucket-major coalesced writes of (src<<8 | dstLow).
__global__ void __launch_bounds__(512) k_scatter(const int* __restrict__ ei, int E,
                                                 int nb_buckets, int chunk,
                                                 const int* __restrict__ offT,
                                                 int* __restrict__ temp) {
  __shared__ int sh[512];
  __shared__ int lofs[MAXNB];
  __shared__ int lcur[MAXNB];
  __shared__ int gbase[MAXNB];
  __shared__ int sorted[SCAP];
  __shared__ unsigned short sbkt[SCAP];
  int g = blockIdx.x, t = threadIdx.x;
  int e0 = g * chunk, e1 = min(e0 + chunk, E);
  int total = e1 - e0;

  if (total > SCAP) {  // safety fallback: direct scatter
    for (int i = t; i < nb_buckets; i += 512) lcur[i] = offT[(size_t)g * nb_buckets + i];
    __syncthreads();
    for (int e = e0 + t; e < e1; e += 512) {
      int s = ei[e];
      int d = ei[E + e];
      int b = d >> BSH;
      int pos = atomicAdd(&lcur[b], 1);
      temp[pos] = (s << BSH) | (d & ((1 << BSH) - 1));
    }
    return;
  }

  lcur[t] = 0;
  __syncthreads();
  for (int e = e0 + t; e < e1; e += 512)
    atomicAdd(&lcur[ei[E + e] >> BSH], 1);
  __syncthreads();
  int v = (t < nb_buckets) ? lcur[t] : 0;
  sh[t] = v;
  __syncthreads();
  for (int off = 1; off < 512; off <<= 1) {
    int u = (t >= off) ? sh[t - off] : 0;
    __syncthreads();
    sh[t] += u;
    __syncthreads();
  }
  if (t < nb_buckets) {
    int excl = sh[t] - v;
    lofs[t] = excl;
    lcur[t] = excl;
    gbase[t] = offT[(size_t)g * nb_buckets + t];
  }
  __syncthreads();
  for (int e = e0 + t; e < e1; e += 512) {
    int s = ei[e];
    int d = ei[E + e];
    int b = d >> BSH;
    int pos = atomicAdd(&lcur[b], 1);
    sorted[pos] = (s << BSH) | (d & ((1 << BSH) - 1));
    sbkt[pos] = (unsigned short)b;
  }
  __syncthreads();
  for (int i = t; i < total; i += 512) {
    int b = sbkt[i];
    temp[gbase[b] + (i - lofs[b])] = sorted[i];
  }
}

// ---------------- pre-transform: y = fp16(x @ Wl0) (layer 0 only) ----------------

__global__ void k_xform32h(const float* __restrict__ xin,
                           const float* __restrict__ Wl,
                           __half* __restrict__ y, int n) {
  __shared__ float sWl[32 * 16];
  int t = threadIdx.x;
  for (int i = t; i < 32 * 16; i += 256) sWl[i] = Wl[i];
  __syncthreads();
  int l = t & 15;
  int base = (t & 63) & ~15;
  int node = (blockIdx.x * 256 + t) >> 4;
  if (node >= n) return;
  float x0 = xin[node * 32 + l];
  float x1 = xin[node * 32 + 16 + l];
  float ay = 0.f;
  #pragma unroll
  for (int i = 0; i < 16; ++i) {
    float v0 = __shfl(x0, base + i, 64);
    float v1 = __shfl(x1, base + i, 64);
    ay += v0 * sWl[i * 16 + l] + v1 * sWl[(16 + i) * 16 + l];
  }
  y[node * 16 + l] = __float2half_rn(ay);
}

// ---------------- edge-parallel aggregation (one block per bucket) ----------------
// Consumes temp directly (no fine sort / csr needed). Each thread owns whole
// edges: read 32B y16 row, fire 16 non-returning LDS float atomics into
// acc[dstLow][*] (stride 17 -> bank-spread). Epilogue: 2 threads/node do
// mean + root matmul + ELU + coalesced store, optionally fused next-y xform.

template <int DI, bool FUSE>
__global__ void __launch_bounds__(512) k_aggB(
    const __half* __restrict__ y, const float* __restrict__ hin,
    const float* __restrict__ Wr, const float* __restrict__ bias,
    const float* __restrict__ Wlnext,
    const int* __restrict__ temp, const int* __restrict__ offT,
    int nb_buckets, int E, int n,
    float* __restrict__ outp, __half* __restrict__ ynext) {
  __shared__ float acc[256 * 17];
  __shared__ int dcnt[256];
  __shared__ __align__(16) float sWr[DI * 16];
  __shared__ float sWl[16 * 16];
  __shared__ float sb[16];
  int b = blockIdx.x, t = threadIdx.x;
  for (int i = t; i < 256 * 17; i += 512) acc[i] = 0.f;
  if (t < 256) dcnt[t] = 0;
  for (int i = t; i < DI * 16; i += 512) sWr[i] = Wr[i];
  if (t < 16) sb[t] = bias[t];
  if (FUSE && t < 256) sWl[t] = Wlnext[t];
  __syncthreads();

  int lo = offT[b];                                    // g=0 row = bucket start
  int hi = (b == nb_buckets - 1) ? E : offT[b + 1];
  for (int e = lo + t; e < hi; e += 512) {
    int p = temp[e];
    int src = p >> BSH;
    int dl = p & 255;
    const uint4* yr = reinterpret_cast<const uint4*>(y + (size_t)src * 16);
    uint4 h0 = yr[0];
    uint4 h1 = yr[1];
    float* arow = &acc[dl * 17];
    float2 f;
    f = __half22float2(*reinterpret_cast<const __half2*>(&h0.x)); atomicAdd(&arow[0], f.x);  atomicAdd(&arow[1], f.y);
    f = __half22float2(*reinterpret_cast<const __half2*>(&h0.y)); atomicAdd(&arow[2], f.x);  atomicAdd(&arow[3], f.y);
    f = __half22float2(*reinterpret_cast<const __half2*>(&h0.z)); atomicAdd(&arow[4], f.x);  atomicAdd(&arow[5], f.y);
    f = __half22float2(*reinterpret_cast<const __half2*>(&h0.w)); atomicAdd(&arow[6], f.x);  atomicAdd(&arow[7], f.y);
    f = __half22float2(*reinterpret_cast<const __half2*>(&h1.x)); atomicAdd(&arow[8], f.x);  atomicAdd(&arow[9], f.y);
    f = __half22float2(*reinterpret_cast<const __half2*>(&h1.y)); atomicAdd(&arow[10], f.x); atomicAdd(&arow[11], f.y);
    f = __half22float2(*reinterpret_cast<const __half2*>(&h1.z)); atomicAdd(&arow[12], f.x); atomicAdd(&arow[13], f.y);
    f = __half22float2(*reinterpret_cast<const __half2*>(&h1.w)); atomicAdd(&arow[14], f.x); atomicAdd(&arow[15], f.y);
    atomicAdd(&dcnt[dl], 1);
  }
  __syncthreads();

  // epilogue: 2 threads per node, 8 channels each
  int nd = t >> 1;
  int cb = (t & 1) * 8;
  int node = (b << BSH) + nd;
  bool valid = node < n;
  float o[8];
  if (valid) {
    float invd = 1.f / fmaxf((float)dcnt[nd], 1.f);
    #pragma unroll
    for (int c = 0; c < 8; ++c) o[c] = acc[nd * 17 + cb + c] * invd + sb[cb + c];
    #pragma unroll 4
    for (int i = 0; i < DI; ++i) {
      float hv = hin[(size_t)node * DI + i];
      #pragma unroll
      for (int c = 0; c < 8; ++c) o[c] += hv * sWr[i * 16 + cb + c];
    }
    #pragma unroll
    for (int c = 0; c < 8; ++c) {
      float v = o[c];
      o[c] = v > 0.f ? v : (__expf(v) - 1.f);
    }
    float4 o0 = {o[0], o[1], o[2], o[3]};
    float4 o1 = {o[4], o[5], o[6], o[7]};
    *reinterpret_cast<float4*>(&outp[(size_t)node * 16 + cb]) = o0;
    *reinterpret_cast<float4*>(&outp[(size_t)node * 16 + cb + 4]) = o1;
  }

  if (FUSE) {
    __syncthreads();
    if (valid) {
      #pragma unroll
      for (int c = 0; c < 8; ++c) acc[nd * 17 + cb + c] = o[c];
    }
    __syncthreads();
    if (valid) {
      float ya[8] = {0.f, 0.f, 0.f, 0.f, 0.f, 0.f, 0.f, 0.f};
      #pragma unroll
      for (int i = 0; i < 16; ++i) {
        float ov = acc[nd * 17 + i];
        #pragma unroll
        for (int c = 0; c < 8; ++c) ya[c] += ov * sWl[i * 16 + cb + c];
      }
      __half2 hh[4];
      #pragma unroll
      for (int c = 0; c < 4; ++c) hh[c] = __floats2half2_rn(ya[2 * c], ya[2 * c + 1]);
      *reinterpret_cast<uint4*>(&ynext[(size_t)node * 16 + cb]) =
          *reinterpret_cast<uint4*>(hh);
    }
  }
}

// ---------------- fused 4-layer MLP via MFMA (working, round-10) ----------------

typedef _Float16 f16x4 __attribute__((ext_vector_type(4)));
typedef float f32x4 __attribute__((ext_vector_type(4)));

#define MFMA16(a, b, c) __builtin_amdgcn_mfma_f32_16x16x16f16(a, b, c, 0, 0, 0)
#define CSTRIDE 20  // halves per LDS column slot

__global__ void __launch_bounds__(256) k_mlp(
    const float* __restrict__ xin,
    const float* __restrict__ W0, const float* __restrict__ B0,
    const float* __restrict__ W1, const float* __restrict__ B1,
    const float* __restrict__ W2, const float* __restrict__ B2,
    const float* __restrict__ W3, const float* __restrict__ B3,
    float* __restrict__ out, int n, int nchunks) {
  __shared__ __align__(16) _Float16 hbuf[4][2][64 * CSTRIDE];  // 20.5 KB
  int t = threadIdx.x;
  int w = t >> 6;        // wave in block
  int lane = t & 63;
  int row = lane & 15;   // A-row / D-col index
  int kg = lane >> 4;    // k-group

  f16x4 b0f[4], b1f[4][4], b2f[4][4], b3f[4];
  float bs0[4], bs1v[4], bs2v[4];
  #pragma unroll
  for (int nt = 0; nt < 4; ++nt) {
    #pragma unroll
    for (int j = 0; j < 4; ++j)
      b0f[nt][j] = (_Float16)W0[(kg * 4 + j) * 64 + nt * 16 + row];
    bs0[nt] = B0[nt * 16 + row];
    bs1v[nt] = B1[nt * 16 + row];
    bs2v[nt] = B2[nt * 16 + row];
  }
  #pragma unroll
  for (int ks = 0; ks < 4; ++ks)
    #pragma unroll
    for (int nt = 0; nt < 4; ++nt)
      #pragma unroll
      for (int j = 0; j < 4; ++j) {
        b1f[ks][nt][j] = (_Float16)W1[(ks * 16 + kg * 4 + j) * 64 + nt * 16 + row];
        b2f[ks][nt][j] = (_Float16)W2[(ks * 16 + kg * 4 + j) * 64 + nt * 16 + row];
      }
  #pragma unroll
  for (int ks = 0; ks < 4; ++ks)
    #pragma unroll
    for (int j = 0; j < 4; ++j)
      b3f[ks][j] = (row < 4) ? (_Float16)W3[(ks * 16 + kg * 4 + j) * 4 + row]
                             : (_Float16)0.f;
  float bs3 = (row < 4) ? B3[row] : 0.f;

  _Float16* hb0 = &hbuf[w][0][0];
  _Float16* hb1 = &hbuf[w][1][0];

  for (int c = blockIdx.x; c < nchunks; c += gridDim.x) {
    int nodeBase = c * 64 + w * 16;
    if (nodeBase >= n) continue;

    int nd = nodeBase + row;
    if (nd >= n) nd = n - 1;
    float4 xv = *reinterpret_cast<const float4*>(&xin[nd * 16 + kg * 4]);
    f16x4 a0;
    a0[0] = (_Float16)xv.x; a0[1] = (_Float16)xv.y;
    a0[2] = (_Float16)xv.z; a0[3] = (_Float16)xv.w;
    #pragma unroll
    for (int nt = 0; nt < 4; ++nt) {
      f32x4 acc = {bs0[nt], bs0[nt], bs0[nt], bs0[nt]};
      acc = MFMA16(a0, b0f[nt], acc);
      f16x4 hv;
      #pragma unroll
      for (int i = 0; i < 4; ++i) {
        float v = acc[i];
        v = v > 0.f ? v : (__expf(v) - 1.f);
        hv[i] = (_Float16)v;
      }
      *reinterpret_cast<f16x4*>(&hb0[(nt * 16 + row) * CSTRIDE + kg * 4]) = hv;
    }

    {
      f16x4 a[4];
      #pragma unroll
      for (int ks = 0; ks < 4; ++ks)
        #pragma unroll
        for (int j = 0; j < 4; ++j)
          a[ks][j] = hb0[(ks * 16 + kg * 4 + j) * CSTRIDE + row];
      #pragma unroll
      for (int nt = 0; nt < 4; ++nt) {
        f32x4 acc = {bs1v[nt], bs1v[nt], bs1v[nt], bs1v[nt]};
        #pragma unroll
        for (int ks = 0; ks < 4; ++ks) acc = MFMA16(a[ks], b1f[ks][nt], acc);
        f16x4 hv;
        #pragma unroll
        for (int i = 0; i < 4; ++i) {
          float v = acc[i];
          v = v > 0.f ? v : (__expf(v) - 1.f);
          hv[i] = (_Float16)v;
        }
        *reinterpret_cast<f16x4*>(&hb1[(nt * 16 + row) * CSTRIDE + kg * 4]) = hv;
      }
    }

    {
      f16x4 a[4];
      #pragma unroll
      for (int ks = 0; ks < 4; ++ks)
        #pragma unroll
        for (int j = 0; j < 4; ++j)
          a[ks][j] = hb1[(ks * 16 + kg * 4 + j) * CSTRIDE + row];
      #pragma unroll
      for (int nt = 0; nt < 4; ++nt) {
        f32x4 acc = {bs2v[nt], bs2v[nt], bs2v[nt], bs2v[nt]};
        #pragma unroll
        for (int ks = 0; ks < 4; ++ks) acc = MFMA16(a[ks], b2f[ks][nt], acc);
        f16x4 hv;
        #pragma unroll
        for (int i = 0; i < 4; ++i) {
          float v = acc[i];
          v = v > 0.f ? v : (__expf(v) - 1.f);
          hv[i] = (_Float16)v;
        }
        *reinterpret_cast<f16x4*>(&hb0[(nt * 16 + row) * CSTRIDE + kg * 4]) = hv;
      }
    }

    {
      f16x4 a[4];
      #pragma unroll
      for (int ks = 0; ks < 4; ++ks)
        #pragma unroll
        for (int j = 0; j < 4; ++j)
          a[ks][j] = hb0[(ks * 16 + kg * 4 + j) * CSTRIDE + row];
      f32x4 acc = {bs3, bs3, bs3, bs3};
      #pragma unroll
      for (int ks = 0; ks < 4; ++ks) acc = MFMA16(a[ks], b3f[ks], acc);
      if (row < 4) {
        #pragma unroll
        for (int i = 0; i < 4; ++i) {
          int nd2 = nodeBase + kg * 4 + i;
          if (nd2 < n) out[nd2 * 4 + row] = acc[i];
        }
      }
    }
  }
}

// ---------------- launch ----------------

extern "C" void kernel_launch(void* const* d_in, const int* in_sizes, int n_in,
                              void* d_out, int out_size, void* d_ws, size_t ws_size,
                              hipStream_t stream) {
  const float* x   = (const float*)d_in[0];
  const int*   ei  = (const int*)d_in[1];
  const float* Wl0 = (const float*)d_in[2];
  const float* Wr0 = (const float*)d_in[3];
  const float* bl0 = (const float*)d_in[4];
  const float* Wl1 = (const float*)d_in[5];
  const float* Wr1 = (const float*)d_in[6];
  const float* bl1 = (const float*)d_in[7];
  const float* Wl2 = (const float*)d_in[8];
  const float* Wr2 = (const float*)d_in[9];
  const float* bl2 = (const float*)d_in[10];
  const float* LW0 = (const float*)d_in[11];
  const float* LB0 = (const float*)d_in[12];
  const float* LW1 = (const float*)d_in[13];
  const float* LB1 = (const float*)d_in[14];
  const float* LW2 = (const float*)d_in[15];
  const float* LB2 = (const float*)d_in[16];
  const float* LW3 = (const float*)d_in[17];
  const float* LB3 = (const float*)d_in[18];
  float* out = (float*)d_out;

  const int N_ = in_sizes[0] / 32;   // 100000
  const int E_ = in_sizes[1] / 2;    // 3200000

  const int NB = (N_ + (1 << BSH) - 1) >> BSH;        // 391 buckets
  const int chunk = (E_ + GPART - 1) / GPART;          // 6250 <= SCAP
  const int n2 = NB * GPART;                           // 200192
  const int nb2 = (n2 + 255) / 256;                    // 782 <= 1024

  char* wsp = (char*)d_ws;
  int* cnt    = (int*)wsp;  wsp += sizeof(int) * (size_t)n2;
  int* offT   = (int*)wsp;  wsp += sizeof(int) * (size_t)n2;
  int* part   = (int*)wsp;  wsp += sizeof(int) * 1024;
  int* temp   = (int*)wsp;  wsp += sizeof(int) * (size_t)E_;   // persists through convs
  size_t hBytes = sizeof(float) * (size_t)N_ * DCONV;          // 6.4 MB
  size_t yBytes = sizeof(__half) * (size_t)N_ * DCONV;         // 3.2 MB
  float*  Ha   = (float*)wsp;  wsp += hBytes;
  float*  Hb   = (float*)wsp;  wsp += hBytes;
  __half* y16a = (__half*)wsp; wsp += yBytes;
  __half* y16b = (__half*)wsp; wsp += yBytes;

  // bucket-partitioned edge list build (no fine sort needed anymore)
  k_hist<<<GPART, 512, 0, stream>>>(ei, E_, NB, chunk, cnt);
  k_block_sums<<<nb2, 256, 0, stream>>>(cnt, n2, part);
  k_scan_part<<<1, 1024, 0, stream>>>(part, nb2);
  k_excl_apply<<<nb2, 256, 0, stream>>>(cnt, n2, part, offT, NB);
  k_scatter<<<GPART, 512, 0, stream>>>(ei, E_, NB, chunk, offT, temp);

  int nbX = (N_ * 16 + 255) / 256;

  // conv0: x -> Ha ; fused -> y16b (= Ha @ Wl1)
  k_xform32h<<<nbX, 256, 0, stream>>>(x, Wl0, y16a, N_);
  k_aggB<32, true><<<NB, 512, 0, stream>>>(y16a, x, Wr0, bl0, Wl1, temp, offT, NB, E_, N_, Ha, y16b);
  // conv1: Ha -> Hb ; fused -> y16a (= Hb @ Wl2)
  k_aggB<16, true><<<NB, 512, 0, stream>>>(y16b, Ha, Wr1, bl1, Wl2, temp, offT, NB, E_, N_, Hb, y16a);
  // conv2: Hb -> Ha
  k_aggB<16, false><<<NB, 512, 0, stream>>>(y16a, Hb, Wr2, bl2, nullptr, temp, offT, NB, E_, N_, Ha, nullptr);

  // MLP: MFMA, one wave per 16 nodes, grid-stride
  int nchunks = (N_ + 63) / 64;      // 1563
  int nbM = 512;
  if (nbM > nchunks) nbM = nchunks;
  k_mlp<<<nbM, 256, 0, stream>>>(Ha, LW0, LB0, LW1, LB1, LW2, LB2, LW3, LB3, out, N_, nchunks);
}

// Round 16
// 169.436 us; speedup vs baseline: 6.4394x; 6.4394x over previous
//
#include <hip/hip_runtime.h>
#include <hip/hip_fp16.h>
#include <math.h>

#define DCONV 16
#define BSH 8            // nodes per bucket = 256
#define GPART 512        // partition blocks (parallelism for hist/scatter)
#define GSH 9            // log2(GPART)
#define MAXNB 512
#define SCAP 6912        // >= chunk (6250) : per-block LDS sort capacity
#define FCAP 12288       // >= max bucket size (~8192 + margin)

// ---------------- bucketed CSR build ----------------

__global__ void __launch_bounds__(512) k_hist(const int* __restrict__ ei, int E,
                                              int nb_buckets, int chunk,
                                              int* __restrict__ cnt) {
  __shared__ int hist[MAXNB];
  int g = blockIdx.x;
  for (int i = threadIdx.x; i < nb_buckets; i += 512) hist[i] = 0;
  __syncthreads();
  int e0 = g * chunk, e1 = min(e0 + chunk, E);
  for (int e = e0 + threadIdx.x; e < e1; e += 512)
    atomicAdd(&hist[ei[E + e] >> BSH], 1);
  __syncthreads();
  for (int i = threadIdx.x; i < nb_buckets; i += 512)
    cnt[i * GPART + g] = hist[i];
}

__global__ void k_block_sums(const int* __restrict__ in, int n, int* __restrict__ part) {
  int i = blockIdx.x * 256 + threadIdx.x;
  int v = (i < n) ? in[i] : 0;
  #pragma unroll
  for (int off = 32; off > 0; off >>= 1) v += __shfl_down(v, off, 64);
  __shared__ int ws[4];
  if ((threadIdx.x & 63) == 0) ws[threadIdx.x >> 6] = v;
  __syncthreads();
  if (threadIdx.x == 0) part[blockIdx.x] = ws[0] + ws[1] + ws[2] + ws[3];
}

// single block, 1024 threads; nb <= 1024
__global__ void k_scan_part(int* __restrict__ part, int nb) {
  __shared__ int s[1024];
  int t = threadIdx.x;
  int v = (t < nb) ? part[t] : 0;
  s[t] = v;
  __syncthreads();
  for (int off = 1; off < 1024; off <<= 1) {
    int u = (t >= off) ? s[t - off] : 0;
    __syncthreads();
    s[t] += u;
    __syncthreads();
  }
  if (t < nb) part[t] = s[t] - v;  // exclusive prefix
}

// writes TRANSPOSED offsets: offT[g * nb_buckets + b]
__global__ void k_excl_apply(const int* __restrict__ in, int n, const int* __restrict__ part,
                             int* __restrict__ outT, int nb_buckets) {
  __shared__ int s[256];
  int t = threadIdx.x;
  int i = blockIdx.x * 256 + t;
  int v = (i < n) ? in[i] : 0;
  s[t] = v;
  __syncthreads();
  for (int off = 1; off < 256; off <<= 1) {
    int u = (t >= off) ? s[t - off] : 0;
    __syncthreads();
    s[t] += u;
    __syncthreads();
  }
  if (i < n) {
    int excl = s[t] - v + part[blockIdx.x];
    int b = i >> GSH;
    int g = i & (GPART - 1);
    outT[g * nb_buckets + b] = excl;
  }
}

// LDS batch-sort scatter: bucket-major coalesced writes of (src<<8 | dstLow).
__global__ void __launch_bounds__(512) k_scatter(const int* __restrict__ ei, int E,
                                                 int nb_buckets, int chunk,
                                                 const int* __restrict__ offT,
                                                 int* __restrict__ temp) {
  __shared__ int sh[512];
  __shared__ int lofs[MAXNB];
  __shared__ int lcur[MAXNB];
  __shared__ int gbase[MAXNB];
  __shared__ int sorted[SCAP];
  __shared__ unsigned short sbkt[SCAP];
  int g = blockIdx.x, t = threadIdx.x;
  int e0 = g * chunk, e1 = min(e0 + chunk, E);
  int total = e1 - e0;

  if (total > SCAP) {  // safety fallback: direct scatter
    for (int i = t; i < nb_buckets; i += 512) lcur[i] = offT[(size_t)g * nb_buckets + i];
    __syncthreads();
    for (int e = e0 + t; e < e1; e += 512) {
      int s = ei[e];
      int d = ei[E + e];
      int b = d >> BSH;
      int pos = atomicAdd(&lcur[b], 1);
      temp[pos] = (s << BSH) | (d & ((1 << BSH) - 1));
    }
    return;
  }

  lcur[t] = 0;
  __syncthreads();
  for (int e = e0 + t; e < e1; e += 512)
    atomicAdd(&lcur[ei[E + e] >> BSH], 1);
  __syncthreads();
  int v = (t < nb_buckets) ? lcur[t] : 0;
  sh[t] = v;
  __syncthreads();
  for (int off = 1; off < 512; off <<= 1) {
    int u = (t >= off) ? sh[t - off] : 0;
    __syncthreads();
    sh[t] += u;
    __syncthreads();
  }
  if (t < nb_buckets) {
    int excl = sh[t] - v;
    lofs[t] = excl;
    lcur[t] = excl;
    gbase[t] = offT[(size_t)g * nb_buckets + t];
  }
  __syncthreads();
  for (int e = e0 + t; e < e1; e += 512) {
    int s = ei[e];
    int d = ei[E + e];
    int b = d >> BSH;
    int pos = atomicAdd(&lcur[b], 1);
    sorted[pos] = (s << BSH) | (d & ((1 << BSH) - 1));
    sbkt[pos] = (unsigned short)b;
  }
  __syncthreads();
  for (int i = t; i < total; i += 512) {
    int b = sbkt[i];
    temp[gbase[b] + (i - lofs[b])] = sorted[i];
  }
}

// per-bucket fine sort: scatter into LDS, then stream csr out sequentially.
__global__ void __launch_bounds__(512) k_fine(const int* __restrict__ temp,
                                              const int* __restrict__ offT,
                                              int nb_buckets, int E, int n,
                                              int* __restrict__ rowptr, int* __restrict__ csr) {
  __shared__ int hist[1 << BSH];
  __shared__ int cur[1 << BSH];
  __shared__ int sorted[FCAP];
  int b = blockIdx.x, t = threadIdx.x;
  int lo = offT[b];                                      // g=0 row of offT
  int hi = (b == nb_buckets - 1) ? E : offT[b + 1];
  int cntb = hi - lo;
  if (t < 256) hist[t] = 0;
  __syncthreads();
  for (int e = lo + t; e < hi; e += 512)
    atomicAdd(&hist[temp[e] & 255], 1);
  __syncthreads();
  int v = 0;
  if (t < 256) { v = hist[t]; cur[t] = v; }
  __syncthreads();
  for (int offm = 1; offm < 256; offm <<= 1) {
    int u = (t >= offm && t < 256) ? cur[t - offm] : 0;
    __syncthreads();
    if (t < 256) cur[t] += u;
    __syncthreads();
  }
  bool inlds = (cntb <= FCAP);
  if (t < 256) {
    int excl = cur[t] - v;
    int node = (b << BSH) + t;
    if (node < n) rowptr[node] = lo + excl;
    cur[t] = inlds ? excl : (lo + excl);
  }
  if (b == nb_buckets - 1 && t == 0) rowptr[n] = hi;
  __syncthreads();
  if (inlds) {
    for (int e = lo + t; e < hi; e += 512) {
      int p = temp[e];
      int pos = atomicAdd(&cur[p & 255], 1);
      sorted[pos] = p >> BSH;
    }
    __syncthreads();
    for (int i = t; i < cntb; i += 512) csr[lo + i] = sorted[i];
  } else {
    for (int e = lo + t; e < hi; e += 512) {
      int p = temp[e];
      int pos = atomicAdd(&cur[p & 255], 1);
      csr[pos] = p >> BSH;
    }
  }
}

// ---------------- pre-transform: y = fp16(x @ Wl0) (layer 0 only) ----------------

__global__ void k_xform32h(const float* __restrict__ xin,
                           const float* __restrict__ Wl,
                           __half* __restrict__ y, int n) {
  __shared__ float sWl[32 * 16];
  int t = threadIdx.x;
  for (int i = t; i < 32 * 16; i += 256) sWl[i] = Wl[i];
  __syncthreads();
  int l = t & 15;
  int base = (t & 63) & ~15;
  int node = (blockIdx.x * 256 + t) >> 4;
  if (node >= n) return;
  float x0 = xin[node * 32 + l];
  float x1 = xin[node * 32 + 16 + l];
  float ay = 0.f;
  #pragma unroll
  for (int i = 0; i < 16; ++i) {
    float v0 = __shfl(x0, base + i, 64);
    float v1 = __shfl(x1, base + i, 64);
    ay += v0 * sWl[i * 16 + l] + v1 * sWl[(16 + i) * 16 + l];
  }
  y[node * 16 + l] = __float2half_rn(ay);
}

// ---------------- aggregate: h_out = elu(mean_gather(y16) + h@Wr + b), optionally
// fused with the NEXT layer's xform. 16 lanes/node: lane = (channel-quad l,
// edge-quarter q); quarters merge via shfl_xor(4)+shfl_xor(8). Gather walk
// unrolled 8-deep: a whole quarter's loads issue in one batch (max MLP).

template <int DI, bool FUSE>
__global__ void k_agg(const __half* __restrict__ y, const float* __restrict__ hin,
                      const float* __restrict__ Wr, const float* __restrict__ bias,
                      const float* __restrict__ Wlnext,
                      const int* __restrict__ rowptr, const int* __restrict__ csr,
                      float* __restrict__ outp, __half* __restrict__ ynext, int n) {
  __shared__ __align__(16) float sWr[DI * 16];
  __shared__ float sb[16];
  __shared__ float sWl[16 * 16];
  {
    int tt = threadIdx.x;
    for (int i = tt; i < DI * 16; i += 256) sWr[i] = Wr[i];
    if (tt < 16) sb[tt] = bias[tt];
    if (FUSE) sWl[tt] = Wlnext[tt];
  }
  __syncthreads();

  int t = blockIdx.x * 256 + threadIdx.x;
  int l = t & 3;               // channel quad
  int q = (t >> 2) & 3;        // edge quarter
  int node = t >> 4;
  if (node >= n) return;
  int r0 = rowptr[node], r1 = rowptr[node + 1];
  int deg = r1 - r0;
  int quarter = (deg + 3) >> 2;
  int ks = r0 + q * quarter;
  int ke = min(ks + quarter, r1);

  const uint2* __restrict__ yv = reinterpret_cast<const uint2*>(y);

  float a0 = 0.f, a1 = 0.f, a2 = 0.f, a3 = 0.f;
  float b0 = 0.f, b1 = 0.f, b2 = 0.f, b3 = 0.f;
  float c0 = 0.f, c1 = 0.f, c2 = 0.f, c3 = 0.f;
  float d0 = 0.f, d1 = 0.f, d2 = 0.f, d3 = 0.f;
  int k = ks;
  for (; k + 7 < ke; k += 8) {
    int ia = csr[k],     ib = csr[k + 1], ic = csr[k + 2], id = csr[k + 3];
    int ie = csr[k + 4], if_ = csr[k + 5], ig = csr[k + 6], ih = csr[k + 7];
    uint2 ra = yv[ia * 4 + l];
    uint2 rb = yv[ib * 4 + l];
    uint2 rc = yv[ic * 4 + l];
    uint2 rd = yv[id * 4 + l];
    uint2 re = yv[ie * 4 + l];
    uint2 rf = yv[if_ * 4 + l];
    uint2 rg = yv[ig * 4 + l];
    uint2 rh = yv[ih * 4 + l];
    float2 f0, f1;
    f0 = __half22float2(*reinterpret_cast<const __half2*>(&ra.x));
    f1 = __half22float2(*reinterpret_cast<const __half2*>(&ra.y));
    a0 += f0.x; a1 += f0.y; a2 += f1.x; a3 += f1.y;
    f0 = __half22float2(*reinterpret_cast<const __half2*>(&rb.x));
    f1 = __half22float2(*reinterpret_cast<const __half2*>(&rb.y));
    b0 += f0.x; b1 += f0.y; b2 += f1.x; b3 += f1.y;
    f0 = __half22float2(*reinterpret_cast<const __half2*>(&rc.x));
    f1 = __half22float2(*reinterpret_cast<const __half2*>(&rc.y));
    c0 += f0.x; c1 += f0.y; c2 += f1.x; c3 += f1.y;
    f0 = __half22float2(*reinterpret_cast<const __half2*>(&rd.x));
    f1 = __half22float2(*reinterpret_cast<const __half2*>(&rd.y));
    d0 += f0.x; d1 += f0.y; d2 += f1.x; d3 += f1.y;
    f0 = __half22float2(*reinterpret_cast<const __half2*>(&re.x));
    f1 = __half22float2(*reinterpret_cast<const __half2*>(&re.y));
    a0 += f0.x; a1 += f0.y; a2 += f1.x; a3 += f1.y;
    f0 = __half22float2(*reinterpret_cast<const __half2*>(&rf.x));
    f1 = __half22float2(*reinterpret_cast<const __half2*>(&rf.y));
    b0 += f0.x; b1 += f0.y; b2 += f1.x; b3 += f1.y;
    f0 = __half22float2(*reinterpret_cast<const __half2*>(&rg.x));
    f1 = __half22float2(*reinterpret_cast<const __half2*>(&rg.y));
    c0 += f0.x; c1 += f0.y; c2 += f1.x; c3 += f1.y;
    f0 = __half22float2(*reinterpret_cast<const __half2*>(&rh.x));
    f1 = __half22float2(*reinterpret_cast<const __half2*>(&rh.y));
    d0 += f0.x; d1 += f0.y; d2 += f1.x; d3 += f1.y;
  }
  for (; k + 3 < ke; k += 4) {
    int ia = csr[k], ib = csr[k + 1], ic = csr[k + 2], id = csr[k + 3];
    uint2 ra = yv[ia * 4 + l];
    uint2 rb = yv[ib * 4 + l];
    uint2 rc = yv[ic * 4 + l];
    uint2 rd = yv[id * 4 + l];
    float2 f0, f1;
    f0 = __half22float2(*reinterpret_cast<const __half2*>(&ra.x));
    f1 = __half22float2(*reinterpret_cast<const __half2*>(&ra.y));
    a0 += f0.x; a1 += f0.y; a2 += f1.x; a3 += f1.y;
    f0 = __half22float2(*reinterpret_cast<const __half2*>(&rb.x));
    f1 = __half22float2(*reinterpret_cast<const __half2*>(&rb.y));
    b0 += f0.x; b1 += f0.y; b2 += f1.x; b3 += f1.y;
    f0 = __half22float2(*reinterpret_cast<const __half2*>(&rc.x));
    f1 = __half22float2(*reinterpret_cast<const __half2*>(&rc.y));
    c0 += f0.x; c1 += f0.y; c2 += f1.x; c3 += f1.y;
    f0 = __half22float2(*reinterpret_cast<const __half2*>(&rd.x));
    f1 = __half22float2(*reinterpret_cast<const __half2*>(&rd.y));
    d0 += f0.x; d1 += f0.y; d2 += f1.x; d3 += f1.y;
  }
  for (; k < ke; ++k) {
    int ia = csr[k];
    uint2 ra = yv[ia * 4 + l];
    float2 f0 = __half22float2(*reinterpret_cast<const __half2*>(&ra.x));
    float2 f1 = __half22float2(*reinterpret_cast<const __half2*>(&ra.y));
    a0 += f0.x; a1 += f0.y; a2 += f1.x; a3 += f1.y;
  }
  float s0 = (a0 + b0) + (c0 + d0);
  float s1 = (a1 + b1) + (c1 + d1);
  float s2 = (a2 + b2) + (c2 + d2);
  float s3 = (a3 + b3) + (c3 + d3);

  // root term: quarter q covers input channels [q*DI/4, (q+1)*DI/4); bias once (q=0)
  int cbase = l * 4;
  float4 rr;
  if (q == 0) rr = *reinterpret_cast<const float4*>(&sb[cbase]);
  else        rr = make_float4(0.f, 0.f, 0.f, 0.f);
  const int QD = DI / 4;
  #pragma unroll
  for (int i = 0; i < QD; ++i) {
    int ii = q * QD + i;
    float hv = hin[node * DI + ii];
    float4 w = *reinterpret_cast<const float4*>(&sWr[ii * 16 + cbase]);
    rr.x += hv * w.x; rr.y += hv * w.y; rr.z += hv * w.z; rr.w += hv * w.w;
  }

  // butterfly merge across quarters -> all lanes hold totals
  #pragma unroll
  for (int m = 4; m <= 8; m <<= 1) {
    s0 += __shfl_xor(s0, m, 64);
    s1 += __shfl_xor(s1, m, 64);
    s2 += __shfl_xor(s2, m, 64);
    s3 += __shfl_xor(s3, m, 64);
    rr.x += __shfl_xor(rr.x, m, 64);
    rr.y += __shfl_xor(rr.y, m, 64);
    rr.z += __shfl_xor(rr.z, m, 64);
    rr.w += __shfl_xor(rr.w, m, 64);
  }

  float inv = 1.f / fmaxf((float)deg, 1.f);
  float ax = s0 * inv + rr.x;
  float ay = s1 * inv + rr.y;
  float az = s2 * inv + rr.z;
  float aw = s3 * inv + rr.w;
  float4 o;
  o.x = ax > 0.f ? ax : (__expf(ax) - 1.f);
  o.y = ay > 0.f ? ay : (__expf(ay) - 1.f);
  o.z = az > 0.f ? az : (__expf(az) - 1.f);
  o.w = aw > 0.f ? aw : (__expf(aw) - 1.f);
  if (q == 0) {
    *reinterpret_cast<float4*>(&outp[node * 16 + cbase]) = o;
  }

  if (FUSE) {
    int c = t & 15;
    int grpbase = (threadIdx.x & 63) & ~15;
    float acc = 0.f;
    #pragma unroll
    for (int i = 0; i < 16; ++i) {
      int src = grpbase + (i >> 2);
      float hv;
      switch (i & 3) {
        case 0: hv = __shfl(o.x, src, 64); break;
        case 1: hv = __shfl(o.y, src, 64); break;
        case 2: hv = __shfl(o.z, src, 64); break;
        default: hv = __shfl(o.w, src, 64); break;
      }
      acc += hv * sWl[i * 16 + c];
    }
    ynext[node * 16 + c] = __float2half_rn(acc);
  }
}

// ---------------- fused 4-layer MLP via MFMA (working, round-10) ----------------

typedef _Float16 f16x4 __attribute__((ext_vector_type(4)));
typedef float f32x4 __attribute__((ext_vector_type(4)));

#define MFMA16(a, b, c) __builtin_amdgcn_mfma_f32_16x16x16f16(a, b, c, 0, 0, 0)
#define CSTRIDE 20  // halves per LDS column slot

__global__ void __launch_bounds__(256) k_mlp(
    const float* __restrict__ xin,
    const float* __restrict__ W0, const float* __restrict__ B0,
    const float* __restrict__ W1, const float* __restrict__ B1,
    const float* __restrict__ W2, const float* __restrict__ B2,
    const float* __restrict__ W3, const float* __restrict__ B3,
    float* __restrict__ out, int n, int nchunks) {
  __shared__ __align__(16) _Float16 hbuf[4][2][64 * CSTRIDE];  // 20.5 KB
  int t = threadIdx.x;
  int w = t >> 6;        // wave in block
  int lane = t & 63;
  int row = lane & 15;   // A-row / D-col index
  int kg = lane >> 4;    // k-group

  f16x4 b0f[4], b1f[4][4], b2f[4][4], b3f[4];
  float bs0[4], bs1v[4], bs2v[4];
  #pragma unroll
  for (int nt = 0; nt < 4; ++nt) {
    #pragma unroll
    for (int j = 0; j < 4; ++j)
      b0f[nt][j] = (_Float16)W0[(kg * 4 + j) * 64 + nt * 16 + row];
    bs0[nt] = B0[nt * 16 + row];
    bs1v[nt] = B1[nt * 16 + row];
    bs2v[nt] = B2[nt * 16 + row];
  }
  #pragma unroll
  for (int ks = 0; ks < 4; ++ks)
    #pragma unroll
    for (int nt = 0; nt < 4; ++nt)
      #pragma unroll
      for (int j = 0; j < 4; ++j) {
        b1f[ks][nt][j] = (_Float16)W1[(ks * 16 + kg * 4 + j) * 64 + nt * 16 + row];
        b2f[ks][nt][j] = (_Float16)W2[(ks * 16 + kg * 4 + j) * 64 + nt * 16 + row];
      }
  #pragma unroll
  for (int ks = 0; ks < 4; ++ks)
    #pragma unroll
    for (int j = 0; j < 4; ++j)
      b3f[ks][j] = (row < 4) ? (_Float16)W3[(ks * 16 + kg * 4 + j) * 4 + row]
                             : (_Float16)0.f;
  float bs3 = (row < 4) ? B3[row] : 0.f;

  _Float16* hb0 = &hbuf[w][0][0];
  _Float16* hb1 = &hbuf[w][1][0];

  for (int c = blockIdx.x; c < nchunks; c += gridDim.x) {
    int nodeBase = c * 64 + w * 16;
    if (nodeBase >= n) continue;

    int nd = nodeBase + row;
    if (nd >= n) nd = n - 1;
    float4 xv = *reinterpret_cast<const float4*>(&xin[nd * 16 + kg * 4]);
    f16x4 a0;
    a0[0] = (_Float16)xv.x; a0[1] = (_Float16)xv.y;
    a0[2] = (_Float16)xv.z; a0[3] = (_Float16)xv.w;
    #pragma unroll
    for (int nt = 0; nt < 4; ++nt) {
      f32x4 acc = {bs0[nt], bs0[nt], bs0[nt], bs0[nt]};
      acc = MFMA16(a0, b0f[nt], acc);
      f16x4 hv;
      #pragma unroll
      for (int i = 0; i < 4; ++i) {
        float v = acc[i];
        v = v > 0.f ? v : (__expf(v) - 1.f);
        hv[i] = (_Float16)v;
      }
      *reinterpret_cast<f16x4*>(&hb0[(nt * 16 + row) * CSTRIDE + kg * 4]) = hv;
    }

    {
      f16x4 a[4];
      #pragma unroll
      for (int ks = 0; ks < 4; ++ks)
        #pragma unroll
        for (int j = 0; j < 4; ++j)
          a[ks][j] = hb0[(ks * 16 + kg * 4 + j) * CSTRIDE + row];
      #pragma unroll
      for (int nt = 0; nt < 4; ++nt) {
        f32x4 acc = {bs1v[nt], bs1v[nt], bs1v[nt], bs1v[nt]};
        #pragma unroll
        for (int ks = 0; ks < 4; ++ks) acc = MFMA16(a[ks], b1f[ks][nt], acc);
        f16x4 hv;
        #pragma unroll
        for (int i = 0; i < 4; ++i) {
          float v = acc[i];
          v = v > 0.f ? v : (__expf(v) - 1.f);
          hv[i] = (_Float16)v;
        }
        *reinterpret_cast<f16x4*>(&hb1[(nt * 16 + row) * CSTRIDE + kg * 4]) = hv;
      }
    }

    {
      f16x4 a[4];
      #pragma unroll
      for (int ks = 0; ks < 4; ++ks)
        #pragma unroll
        for (int j = 0; j < 4; ++j)
          a[ks][j] = hb1[(ks * 16 + kg * 4 + j) * CSTRIDE + row];
      #pragma unroll
      for (int nt = 0; nt < 4; ++nt) {
        f32x4 acc = {bs2v[nt], bs2v[nt], bs2v[nt], bs2v[nt]};
        #pragma unroll
        for (int ks = 0; ks < 4; ++ks) acc = MFMA16(a[ks], b2f[ks][nt], acc);
        f16x4 hv;
        #pragma unroll
        for (int i = 0; i < 4; ++i) {
          float v = acc[i];
          v = v > 0.f ? v : (__expf(v) - 1.f);
          hv[i] = (_Float16)v;
        }
        *reinterpret_cast<f16x4*>(&hb0[(nt * 16 + row) * CSTRIDE + kg * 4]) = hv;
      }
    }

    {
      f16x4 a[4];
      #pragma unroll
      for (int ks = 0; ks < 4; ++ks)
        #pragma unroll
        for (int j = 0; j < 4; ++j)
          a[ks][j] = hb0[(ks * 16 + kg * 4 + j) * CSTRIDE + row];
      f32x4 acc = {bs3, bs3, bs3, bs3};
      #pragma unroll
      for (int ks = 0; ks < 4; ++ks) acc = MFMA16(a[ks], b3f[ks], acc);
      if (row < 4) {
        #pragma unroll
        for (int i = 0; i < 4; ++i) {
          int nd2 = nodeBase + kg * 4 + i;
          if (nd2 < n) out[nd2 * 4 + row] = acc[i];
        }
      }
    }
  }
}

// ---------------- launch ----------------

extern "C" void kernel_launch(void* const* d_in, const int* in_sizes, int n_in,
                              void* d_out, int out_size, void* d_ws, size_t ws_size,
                              hipStream_t stream) {
  const float* x   = (const float*)d_in[0];
  const int*   ei  = (const int*)d_in[1];
  const float* Wl0 = (const float*)d_in[2];
  const float* Wr0 = (const float*)d_in[3];
  const float* bl0 = (const float*)d_in[4];
  const float* Wl1 = (const float*)d_in[5];
  const float* Wr1 = (const float*)d_in[6];
  const float* bl1 = (const float*)d_in[7];
  const float* Wl2 = (const float*)d_in[8];
  const float* Wr2 = (const float*)d_in[9];
  const float* bl2 = (const float*)d_in[10];
  const float* LW0 = (const float*)d_in[11];
  const float* LB0 = (const float*)d_in[12];
  const float* LW1 = (const float*)d_in[13];
  const float* LB1 = (const float*)d_in[14];
  const float* LW2 = (const float*)d_in[15];
  const float* LB2 = (const float*)d_in[16];
  const float* LW3 = (const float*)d_in[17];
  const float* LB3 = (const float*)d_in[18];
  float* out = (float*)d_out;

  const int N_ = in_sizes[0] / 32;   // 100000
  const int E_ = in_sizes[1] / 2;    // 3200000

  const int NB = (N_ + (1 << BSH) - 1) >> BSH;        // 391 buckets
  const int chunk = (E_ + GPART - 1) / GPART;          // 6250 <= SCAP
  const int n2 = NB * GPART;                           // 200192
  const int nb2 = (n2 + 255) / 256;                    // 782 <= 1024

  char* wsp = (char*)d_ws;
  int* cnt    = (int*)wsp;  wsp += sizeof(int) * (size_t)n2;
  int* offT   = (int*)wsp;  wsp += sizeof(int) * (size_t)n2;
  int* part   = (int*)wsp;  wsp += sizeof(int) * 1024;
  int* temp   = (int*)wsp;  wsp += sizeof(int) * (size_t)E_;   // 12.8 MB, dead after k_fine
  int* csr    = (int*)wsp;  wsp += sizeof(int) * (size_t)E_;
  size_t hBytes = sizeof(float) * (size_t)N_ * DCONV;          // 6.4 MB
  float* Ha   = (float*)wsp; wsp += hBytes;
  int* rowptr = (int*)wsp;  wsp += sizeof(int) * (size_t)(N_ + 1);
  // reuse temp after k_fine: y16a (3.2 MB) + y16b (3.2 MB) + Hb (6.4 MB) = 12.8 MB
  size_t yBytes = sizeof(__half) * (size_t)N_ * DCONV;         // 3.2 MB
  __half* y16a = (__half*)temp;
  __half* y16b = (__half*)((char*)temp + yBytes);
  float*  Hb   = (float*)((char*)temp + 2 * yBytes);

  // CSR build
  k_hist<<<GPART, 512, 0, stream>>>(ei, E_, NB, chunk, cnt);
  k_block_sums<<<nb2, 256, 0, stream>>>(cnt, n2, part);
  k_scan_part<<<1, 1024, 0, stream>>>(part, nb2);
  k_excl_apply<<<nb2, 256, 0, stream>>>(cnt, n2, part, offT, NB);
  k_scatter<<<GPART, 512, 0, stream>>>(ei, E_, NB, chunk, offT, temp);
  k_fine<<<NB, 512, 0, stream>>>(temp, offT, NB, E_, N_, rowptr, csr);

  int nbX = (N_ * 16 + 255) / 256;   // xform grid
  int nbA = (N_ * 16 + 255) / 256;   // agg grid (16 lanes/node)

  // conv0: x -> Ha ; fused xform -> y16b (= Ha @ Wl1)
  k_xform32h<<<nbX, 256, 0, stream>>>(x, Wl0, y16a, N_);
  k_agg<32, true><<<nbA, 256, 0, stream>>>(y16a, x, Wr0, bl0, Wl1, rowptr, csr, Ha, y16b, N_);
  // conv1: Ha -> Hb ; fused xform -> y16a (= Hb @ Wl2)
  k_agg<16, true><<<nbA, 256, 0, stream>>>(y16b, Ha, Wr1, bl1, Wl2, rowptr, csr, Hb, y16a, N_);
  // conv2: Hb -> Ha (no fusion)
  k_agg<16, false><<<nbA, 256, 0, stream>>>(y16a, Hb, Wr2, bl2, nullptr, rowptr, csr, Ha, nullptr, N_);

  // MLP: MFMA, one wave per 16 nodes, grid-stride
  int nchunks = (N_ + 63) / 64;      // 1563
  int nbM = 512;
  if (nbM > nchunks) nbM = nchunks;
  k_mlp<<<nbM, 256, 0, stream>>>(Ha, LW0, LB0, LW1, LB1, LW2, LB2, LW3, LB3, out, N_, nchunks);
}